// Round 5
// baseline (104.078 us; speedup 1.0000x reference)
//
#include <hip/hip_runtime.h>
#include <hip/hip_bf16.h>

#define NROWS 16384
#define DIM 64
#define BCOLS 512                     // cols per block: B tile = 64 KB LDS, staged ONCE
#define BROWS 1024                    // rows per block
#define NCS (NROWS / BCOLS)           // 32 col-splits
#define NRG (NROWS / BROWS)           // 16 row-groups

static constexpr float TAU = 0.28f;
static constexpr float EPS = 1e-8f;
// exp(x/TAU) = exp2(x * log2e / TAU), with 2^23 folded in so the MFMA
// accumulator directly produces the Schraudolph integer argument:
//   exp2(x) ~= bitcast_f32( (int)(x * 2^23) + EXPB )
// EXPB = (127 - 0.05753)*2^23; per-term +-3% error averages out across the
// 16384-term row sum (R4 measured absmax 0.0).
static constexpr float EXP2_SCALE = (float)(8388608.0 / (0.28 * 0.6931471805599453));
static constexpr int   EXPB = 1064870600;
static constexpr float LN2F = 0.69314718055994530942f;

using short8   = __attribute__((ext_vector_type(8))) short;
using f32x4    = __attribute__((ext_vector_type(4))) float;
using ushort4v = __attribute__((ext_vector_type(4))) unsigned short;

typedef __attribute__((address_space(1))) const unsigned char ga_t;
typedef __attribute__((address_space(3))) unsigned char la_t;

// Kernel 1: per-row L2 normalize; emit A = bf16(EXP2_SCALE * u_norm),
// W = bf16(u_norm + i_norm), p[n] = (u_norm . i_norm)/TAU, zero total[n],
// zero done[], zero d_out. Each 16-lane group owns one row.
__global__ __launch_bounds__(256) void prep_kernel(
    const float* __restrict__ u, const float* __restrict__ v,
    __hip_bfloat16* __restrict__ a_out, __hip_bfloat16* __restrict__ w_out,
    float* __restrict__ p_out, float* __restrict__ total,
    int* __restrict__ done, float* __restrict__ out)
{
    const int lane = threadIdx.x & 63;
    const int wv   = threadIdx.x >> 6;
    const int l15  = lane & 15;
    const int row  = blockIdx.x * 16 + wv * 4 + (lane >> 4);

    const float4 uu = *(const float4*)(u + (size_t)row * DIM + l15 * 4);
    const float4 vv = *(const float4*)(v + (size_t)row * DIM + l15 * 4);

    float su = uu.x * uu.x + uu.y * uu.y + uu.z * uu.z + uu.w * uu.w;
    float si = vv.x * vv.x + vv.y * vv.y + vv.z * vv.z + vv.w * vv.w;
    float sd = uu.x * vv.x + uu.y * vv.y + uu.z * vv.z + uu.w * vv.w;
#pragma unroll
    for (int m = 1; m < 16; m <<= 1) {
        su += __shfl_xor(su, m, 64);
        si += __shfl_xor(si, m, 64);
        sd += __shfl_xor(sd, m, 64);
    }
    const float inv_u = 1.0f / fmaxf(sqrtf(su), 1e-12f);
    const float inv_i = 1.0f / fmaxf(sqrtf(si), 1e-12f);

    alignas(8) __hip_bfloat16 a4[4], w4[4];
    const float un[4] = {uu.x * inv_u, uu.y * inv_u, uu.z * inv_u, uu.w * inv_u};
    const float in[4] = {vv.x * inv_i, vv.y * inv_i, vv.z * inv_i, vv.w * inv_i};
#pragma unroll
    for (int r = 0; r < 4; r++) {
        a4[r] = __float2bfloat16(EXP2_SCALE * un[r]);
        w4[r] = __float2bfloat16(un[r] + in[r]);
    }
    *(ushort4v*)((unsigned short*)a_out + (size_t)row * DIM + l15 * 4) = *(ushort4v*)a4;
    *(ushort4v*)((unsigned short*)w_out + (size_t)row * DIM + l15 * 4) = *(ushort4v*)w4;

    if (l15 == 0) {
        p_out[row] = sd * inv_u * inv_i * (1.0f / TAU);
        total[row] = 0.0f;
    }
    if (blockIdx.x == 0 && threadIdx.x < NRG) done[threadIdx.x] = 0;
    if (blockIdx.x == 0 && threadIdx.x == 0) out[0] = 0.0f;
}

// Kernel 2: fused GEMM + Schraudolph-exp + row-sum + INLINE FINALIZE.
// Compute body is the R4 proven skeleton (47.0us), unchanged. After each
// block's total[] atomics drain (__syncthreads -> vmcnt(0)), tid0 bumps
// done[rg] with an agent-scope ACQ_REL fetch_add; the LAST of the 32
// col-split blocks for a row-group (whichever finishes last — no order or
// residency assumption) reads the complete total[] slice via agent-scope
// atomic loads and accumulates mean(log(total+EPS) - p) into out.
// This deletes finalize_kernel (one launch + its gap).
__global__ __launch_bounds__(512, 4) void score_kernel(
    const __hip_bfloat16* __restrict__ A, const __hip_bfloat16* __restrict__ W,
    const float* __restrict__ p, float* __restrict__ total,
    int* __restrict__ done, float* __restrict__ out)
{
    __shared__ alignas(16) ushort blds[BCOLS * DIM];   // exactly 64 KB
    __shared__ float tred[8];
    __shared__ int tlast;

    const int tid  = threadIdx.x;
    const int lane = tid & 63;
    const int wv   = tid >> 6;          // 0..7
    const int l15  = lane & 15;
    const int quad = lane >> 4;
    const int cs   = blockIdx.x & (NCS - 1);
    const int rg   = blockIdx.x >> 5;
    const int col0    = cs * BCOLS;
    const int rowbase = rg * BROWS;

    const ushort* Au = (const ushort*)A;
    const ushort* Wu = (const ushort*)W;

    // Stage B: 4096 16-B chunks; physical slot p -> LDS offset p*16,
    // global chunk c = (p&7) ^ (col&7). Coalesced; XOR-swizzled so every
    // ds_read_b128 below is bank-conflict-free.
#pragma unroll
    for (int q = 0; q < 8; q++) {
        const int pp = q * 512 + tid;
        const int j = pp >> 3;
        const int c = (pp & 7) ^ (j & 7);
        const ushort* g = Wu + (size_t)(col0 + j) * DIM + c * 8;
        __builtin_amdgcn_global_load_lds((ga_t*)g, (la_t*)&blds[(size_t)pp * 8], 16, 0, 0);
    }
    __syncthreads();

#pragma unroll 1
    for (int si = 0; si < 2; si++) {
        const int r0 = rowbase + si * 512 + wv * 64;

        // A fragments: rows r0 + rs*16 + l15, k = kk*32 + quad*8 + [0..7]
        short8 af[4][2];
#pragma unroll
        for (int rs = 0; rs < 4; rs++)
#pragma unroll
            for (int kk = 0; kk < 2; kk++)
                af[rs][kk] = *(const short8*)(
                    Au + (size_t)(r0 + rs * 16 + l15) * DIM + kk * 32 + quad * 8);

        f32x4 rowsum[4];
#pragma unroll
        for (int rs = 0; rs < 4; rs++) rowsum[rs] = {0.f, 0.f, 0.f, 0.f};

#pragma unroll 4
        for (int ct = 0; ct < BCOLS / 16; ct++) {
            const int jl = ct * 16 + l15;
            const int sw = l15 & 7;     // (jl & 7) == (l15 & 7)
            const short8 b0 = *(const short8*)&blds[(size_t)(jl * 8 + (quad ^ sw)) * 8];
            const short8 b1 = *(const short8*)&blds[(size_t)(jl * 8 + ((4 + quad) ^ sw)) * 8];
#pragma unroll
            for (int rs = 0; rs < 4; rs++) {
                f32x4 acc = {0.f, 0.f, 0.f, 0.f};
                acc = __builtin_amdgcn_mfma_f32_16x16x32_bf16(af[rs][0], b0, acc, 0, 0, 0);
                acc = __builtin_amdgcn_mfma_f32_16x16x32_bf16(af[rs][1], b1, acc, 0, 0, 0);
#pragma unroll
                for (int r = 0; r < 4; r++)
                    rowsum[rs][r] += __int_as_float((int)acc[r] + EXPB);
            }
        }

        // Sum over the 16 columns held by each l15-group.
#pragma unroll
        for (int m = 1; m < 16; m <<= 1)
#pragma unroll
            for (int rs = 0; rs < 4; rs++)
#pragma unroll
                for (int r = 0; r < 4; r++)
                    rowsum[rs][r] += __shfl_xor(rowsum[rs][r], m, 64);

        if (l15 == 0) {
#pragma unroll
            for (int rs = 0; rs < 4; rs++)
#pragma unroll
                for (int r = 0; r < 4; r++)
                    atomicAdd(&total[r0 + rs * 16 + quad * 4 + r], rowsum[rs][r]);
        }
    }

    // ---- inline finalize: last col-split block per row-group wins ----
    __syncthreads();   // drains vmcnt: this block's total[] atomics are issued-complete
    if (tid == 0) {
        const int prev = __hip_atomic_fetch_add(&done[rg], 1,
                             __ATOMIC_ACQ_REL, __HIP_MEMORY_SCOPE_AGENT);
        tlast = (prev == NCS - 1) ? 1 : 0;
    }
    __syncthreads();
    if (tlast) {                       // block-uniform branch
        float part = 0.0f;
#pragma unroll
        for (int rr = 0; rr < BROWS / 512; rr++) {
            const int row = rowbase + rr * 512 + tid;
            const float t = __hip_atomic_load(&total[row],
                                __ATOMIC_RELAXED, __HIP_MEMORY_SCOPE_AGENT);
            part += __log2f(t + EPS) * LN2F - p[row];
        }
#pragma unroll
        for (int m = 1; m < 64; m <<= 1) part += __shfl_xor(part, m, 64);
        if (lane == 0) tred[wv] = part;
        __syncthreads();
        if (tid == 0) {
            float s = 0.0f;
#pragma unroll
            for (int i = 0; i < 8; i++) s += tred[i];
            atomicAdd(out, s * (1.0f / (float)NROWS));
        }
    }
}

extern "C" void kernel_launch(void* const* d_in, const int* in_sizes, int n_in,
                              void* d_out, int out_size, void* d_ws, size_t ws_size,
                              hipStream_t stream) {
    const float* u = (const float*)d_in[0];
    const float* v = (const float*)d_in[1];

    char* ws = (char*)d_ws;
    __hip_bfloat16* a = (__hip_bfloat16*)(ws);                                  // 2 MB
    __hip_bfloat16* w = (__hip_bfloat16*)(ws + (size_t)NROWS * DIM * 2);        // 2 MB
    float* p   = (float*)(ws + (size_t)NROWS * DIM * 4);                        // 64 KB
    float* tot = (float*)(ws + (size_t)NROWS * DIM * 4 + (size_t)NROWS * 4);    // 64 KB
    int*   dn  = (int*)(ws + (size_t)NROWS * DIM * 4 + (size_t)NROWS * 8);      // 64 B

    prep_kernel<<<NROWS / 16, 256, 0, stream>>>(u, v, a, w, p, tot, dn, (float*)d_out);
    score_kernel<<<NRG * NCS, 512, 0, stream>>>(a, w, p, tot, dn, (float*)d_out);
}